// Round 3
// baseline (187.351 us; speedup 1.0000x reference)
//
#include <hip/hip_runtime.h>
#include <stdint.h>
#include <stddef.h>

typedef __attribute__((ext_vector_type(8))) short s16x8;
typedef __attribute__((ext_vector_type(4))) short s16x4;
typedef __attribute__((ext_vector_type(4))) float f32x4;

#define B_  2
#define T_  2048
#define E_  1024
#define H_  16
#define E3_ 3072

// fp32 -> bf16, round-to-nearest-even
__device__ __forceinline__ short f2bf(float f) {
  union { float f; uint32_t u; } v; v.f = f;
  uint32_t u = v.u;
  return (short)((u + 0x7FFFu + ((u >> 16) & 1u)) >> 16);
}

__device__ __forceinline__ uint32_t fbits(float f) {
  union { float f; uint32_t u; } v; v.f = f; return v.u;
}

// async global->LDS, 16B per lane; lds dest = wave-uniform base + lane*16
__device__ __forceinline__ void gload_lds16(const short* g, short* l) {
  __builtin_amdgcn_global_load_lds(
      (__attribute__((address_space(1))) void*)(const_cast<short*>(g)),
      (__attribute__((address_space(3))) void*)(l), 16, 0, 0);
}

// ---------------- merged cast kernel (x, w_qkv, w_proj in one launch) -------
// Q-rows of w_qkv (first E rows) pre-scaled by log2(e)/8 so attention can
// call exp2f directly on MFMA output.
__global__ void castk_all(const float* __restrict__ x, const float* __restrict__ wqkv,
                          const float* __restrict__ wproj, short* __restrict__ xb,
                          short* __restrict__ wqkvb, short* __restrict__ wprojb) {
  const int bid = blockIdx.x;
  const float* in; short* out; int i; float sc = 1.0f;
  if (bid < 4096)      { in = x;     out = xb;     i = bid * 256 + threadIdx.x; }
  else if (bid < 7168) { in = wqkv;  out = wqkvb;  i = (bid - 4096) * 256 + threadIdx.x;
                         if (i < 262144) sc = 0.18033688011112042f; }
  else                 { in = wproj; out = wprojb; i = (bid - 7168) * 256 + threadIdx.x; }
  const float4 v = ((const float4*)in)[i];
  s16x4 o;
  o[0] = f2bf(v.x * sc); o[1] = f2bf(v.y * sc);
  o[2] = f2bf(v.z * sc); o[3] = f2bf(v.w * sc);
  ((s16x4*)out)[i] = o;
}

// ---------------- NT GEMM: C[M,N] = A[M,K] * B[N,K]^T (bf16 in, fp32 acc) ---
// MODE 0: fp32 output, plain. MODE 2: qkv mode — bf16 output; V columns
// (col >= 2E) are written TRANSPOSED into vt[b,h,d,t] (packed s16x4 over 4
// consecutive t), Q/K columns go to the qkv buffer. Fuses the old vtrans.
template <int MODE>
__global__ void gemm_nt_128(const short* __restrict__ A, const short* __restrict__ B,
                            void* __restrict__ Cv, short* __restrict__ vt,
                            int M, int N, int K) {
  __shared__ short As[128 * 32];
  __shared__ short Bs[128 * 32];
  const int tid  = threadIdx.x;
  const int lane = tid & 63;
  const int w    = tid >> 6;
  const int quad = lane >> 4;
  const int l16  = lane & 15;
  const int wm   = (w >> 1) * 64;
  const int wn   = (w & 1) * 64;
  const int bm   = blockIdx.y * 128;
  const int bn   = blockIdx.x * 128;

  f32x4 acc[4][4];
#pragma unroll
  for (int i = 0; i < 4; i++)
#pragma unroll
    for (int j = 0; j < 4; j++) acc[i][j] = (f32x4){0.f, 0.f, 0.f, 0.f};

  const int srow = w * 32 + (lane >> 2);
  const int scol = (lane & 3) * 8;
  const short* gA = A + (size_t)(bm + srow) * K + scol;
  const short* gB = B + (size_t)(bn + srow) * K + scol;
  short* lA = As + (w * 32) * 32;
  short* lB = Bs + (w * 32) * 32;

  for (int k0 = 0; k0 < K; k0 += 32) {
    __syncthreads();
    gload_lds16(gA + k0,          lA);
    gload_lds16(gA + 16 * K + k0, lA + 16 * 32);
    gload_lds16(gB + k0,          lB);
    gload_lds16(gB + 16 * K + k0, lB + 16 * 32);
    __syncthreads();

    s16x8 a[4], b[4];
#pragma unroll
    for (int i = 0; i < 4; i++)
      a[i] = *(const s16x8*)&As[(wm + i * 16 + l16) * 32 + quad * 8];
#pragma unroll
    for (int j = 0; j < 4; j++)
      b[j] = *(const s16x8*)&Bs[(wn + j * 16 + l16) * 32 + quad * 8];
#pragma unroll
    for (int i = 0; i < 4; i++)
#pragma unroll
      for (int j = 0; j < 4; j++)
        acc[i][j] = __builtin_amdgcn_mfma_f32_16x16x32_bf16(a[i], b[j], acc[i][j], 0, 0, 0);
  }

  if (MODE == 2 && bn >= 2 * E_) {
    // V block: write transposed to vt[b,h,d,t], 4 consecutive t per store
#pragma unroll
    for (int i = 0; i < 4; i++) {
      const int token = bm + wm + i * 16 + quad * 4;
      const int bb = token >> 11, t = token & (T_ - 1);
#pragma unroll
      for (int j = 0; j < 4; j++) {
        const int col = bn + wn + j * 16 + l16 - 2 * E_;  // h*64 + d
        s16x4 pk;
#pragma unroll
        for (int r = 0; r < 4; r++) pk[r] = f2bf(acc[i][j][r]);
        *(s16x4*)&vt[((size_t)(bb * H_ + (col >> 6)) * 64 + (col & 63)) * T_ + t] = pk;
      }
    }
  } else {
#pragma unroll
    for (int i = 0; i < 4; i++) {
      const int row0 = bm + wm + i * 16 + quad * 4;
#pragma unroll
      for (int j = 0; j < 4; j++) {
        const int col = bn + wn + j * 16 + l16;
#pragma unroll
        for (int r = 0; r < 4; r++) {
          const size_t idx = (size_t)(row0 + r) * N + col;
          if (MODE == 2) ((short*)Cv)[idx] = f2bf(acc[i][j][r]);
          else           ((float*)Cv)[idx] = acc[i][j][r];
        }
      }
    }
  }
}

// ---------------- flash attention -------------------------------------------
// R3: two composable fixes on the measured dominant pipe (LDS ~30us of 43 +
// per-step barrier drain of the prefetch DMA):
//  (a) 32 q-rows/wave x 4 waves = 128-q blocks: K/V fragments read once per
//      wave and reused for 2 q-subtiles -> 20 (was 36) ds_read_b128 per 32 q.
//  (b) T4 counted-vmcnt pipeline: 3 LDS buffers, raw s_barrier, s_waitcnt
//      vmcnt(4) in-loop (tile t's 4 DMAs done, tile t+1's 4 stay IN FLIGHT
//      across the barrier); vmcnt(0) only on the last step. __syncthreads'
//      vmcnt(0)-before-barrier drain was exposing DMA latency every step.
// WAR safety: stage(t+2) overwrites the buffer read at step t-1; those reads
// were consumed into registers before their wave reached the step-t barrier.
// Wait-count robustness: tile t's loads always have >=4 younger vmem ops
// (stage t+1), so "all but newest 4 complete" implies tile t complete even if
// the compiler interleaves unrelated vmem ops.
// Grid 32bh x 16QT = 512 blocks, 2/CU (LDS 64KB: 3x8K K + 3x8K V + 16K P).
// Pairing QT(y)+QT(y+8)=15 -> every CU gets exactly 34 block-steps.
// Waves 0/1 are fully masked on the last kv tile -> skip compute (uniform).
__global__ void __launch_bounds__(256, 2)
attn_kernel(const short* __restrict__ qkv, const short* __restrict__ vt,
            short* __restrict__ attout) {
  __shared__ short Ks[3][64 * 64];  // [kv][d], 16B-chunk swizzled
  __shared__ short Vs[3][64 * 64];  // [d][kv], 16B-chunk swizzled
  __shared__ short Ps[4][32 * 64];  // per-wave [q][kv], 16B-group swizzled
  const int tid  = threadIdx.x;
  const int lane = tid & 63;
  const int w    = tid >> 6;   // 0..3
  const int quad = lane >> 4;
  const int l16  = lane & 15;
  const int bh = blockIdx.x;
  const int b = bh >> 4, h = bh & 15;
  // pairing: CU gets y and y+8 (round-robin, period 256); QT(y)+QT(y+8)=15
  const int y  = blockIdx.y;
  const int QT = (y < 8) ? y : (23 - y);
  const int q0b   = QT * 128;   // block's first q row
  const int kvmax = q0b + 64;   // last kv tile base
  const float NEG_INF = -__builtin_inff();

  const int srl = lane >> 3;
  const int sgc = ((lane & 7) ^ srl) * 8;
  const short* gK = qkv + (size_t)(b * T_) * E3_ + E_ + h * 64 + sgc;
  const short* gV = vt + (size_t)(bh * 64) * T_ + sgc;
  const int swz = (l16 & 7);

  s16x8 ones;
#pragma unroll
  for (int i = 0; i < 8; i++) ones[i] = (short)0x3F80;  // bf16 1.0

  auto stage = [&](int kv0s, int bf) {
#pragma unroll
    for (int i = 0; i < 2; i++) {
      const int r8 = w * 16 + i * 8;  // this wave stages rows r8..r8+7
      gload_lds16(gK + (size_t)(kv0s + r8 + srl) * E3_, &Ks[bf][r8 * 64]);
      gload_lds16(gV + (size_t)(r8 + srl) * T_ + kv0s,  &Vs[bf][r8 * 64]);
    }
  };

  // Q B-fragments for this wave's 32 rows (pre-scaled by log2e/8).
  // Issued before staging so they are oldest in the vmcnt FIFO.
  s16x8 qf[2][2];
#pragma unroll
  for (int sub = 0; sub < 2; sub++) {
    const short* qbase = qkv + (size_t)(b * T_ + q0b + w * 32 + sub * 16 + l16) * E3_ + h * 64 + quad * 8;
    qf[sub][0] = *(const s16x8*)(qbase);
    qf[sub][1] = *(const s16x8*)(qbase + 32);
  }

  f32x4 o[2][4], ol[2];
#pragma unroll
  for (int sub = 0; sub < 2; sub++) {
    ol[sub] = (f32x4){0.f, 0.f, 0.f, 0.f};
#pragma unroll
    for (int j = 0; j < 4; j++) o[sub][j] = (f32x4){0.f, 0.f, 0.f, 0.f};
  }

  // prologue: every block has >= 2 kv tiles (kvmax >= 64)
  stage(0, 0);
  stage(64, 1);

  const int wq    = (w & 1) * 32;            // q offset within the wave's kv tile on diag
  const int wlast = q0b + (w >> 1) * 64;     // this wave's last active kv tile

  int cur = 0, nx2 = 2;
#pragma unroll 1
  for (int kv0 = 0; kv0 <= kvmax; kv0 += 64) {
    // tile kv0's 4 DMAs done; tile kv0+64's 4 stay in flight across barrier
    if (kv0 < kvmax) __asm volatile("s_waitcnt vmcnt(4)" ::: "memory");
    else             __asm volatile("s_waitcnt vmcnt(0)" ::: "memory");
    __builtin_amdgcn_s_barrier();
    __builtin_amdgcn_sched_barrier(0);

    // issue prefetch of tile t+2 into the buffer read at step t-1
    if (kv0 + 128 <= kvmax) stage(kv0 + 128, nx2);

    if (kv0 <= wlast) {  // wave-uniform; skip fully-masked steps
      // S^T: s[sub][j][r] = score[kv=kv0+j*16+quad*4+r][q=q0b+w*32+sub*16+l16]
      f32x4 s[2][4];
#pragma unroll
      for (int sub = 0; sub < 2; sub++)
#pragma unroll
        for (int j = 0; j < 4; j++) s[sub][j] = (f32x4){0.f, 0.f, 0.f, 0.f};

      __builtin_amdgcn_s_setprio(1);
#pragma unroll
      for (int c = 0; c < 2; c++) {
        s16x8 kf[4];  // K fragments, reused for both q-subtiles
#pragma unroll
        for (int j = 0; j < 4; j++)
          kf[j] = *(const s16x8*)&Ks[cur][(j * 16 + l16) * 64 + (((c * 4 + quad) ^ swz) * 8)];
#pragma unroll
        for (int sub = 0; sub < 2; sub++)
#pragma unroll
          for (int j = 0; j < 4; j++)
            s[sub][j] = __builtin_amdgcn_mfma_f32_16x16x32_bf16(kf[j], qf[sub][c], s[sub][j], 0, 0, 0);
      }
      __builtin_amdgcn_s_setprio(0);

      // mask only on this wave's diagonal step
      if (kv0 == wlast) {
#pragma unroll
        for (int sub = 0; sub < 2; sub++)
#pragma unroll
          for (int j = 0; j < 4; j++)
#pragma unroll
            for (int r = 0; r < 4; r++)
              if (j * 16 + quad * 4 + r > wq + sub * 16 + l16) s[sub][j][r] = NEG_INF;
      }

      // exp2 + truncate-pack 4 consecutive kv -> one b64 (v_perm pack)
#pragma unroll
      for (int sub = 0; sub < 2; sub++)
#pragma unroll
        for (int j = 0; j < 4; j++) {
          const float p0 = exp2f(s[sub][j][0]);
          const float p1 = exp2f(s[sub][j][1]);
          const float p2 = exp2f(s[sub][j][2]);
          const float p3 = exp2f(s[sub][j][3]);
          int2 pk;
          pk.x = (int)__builtin_amdgcn_perm(fbits(p1), fbits(p0), 0x07060302u);
          pk.y = (int)__builtin_amdgcn_perm(fbits(p3), fbits(p2), 0x07060302u);
          short* pw = &Ps[w][(sub * 16 + l16) * 64 + (((2 * j + (quad >> 1)) ^ swz) * 8) + (quad & 1) * 4];
          *(int2*)pw = pk;
        }
      // wave-private P: order writes vs cross-lane reads (LDS in-order per wave)
      __asm volatile("s_waitcnt lgkmcnt(0)" ::: "memory");

      // O += P V ; row sums via ones-MFMA; V fragments reused for both subtiles
      __builtin_amdgcn_s_setprio(1);
#pragma unroll
      for (int c = 0; c < 2; c++) {
        s16x8 vf[4];
#pragma unroll
        for (int j = 0; j < 4; j++)
          vf[j] = *(const s16x8*)&Vs[cur][(j * 16 + l16) * 64 + (((c * 4 + quad) ^ swz) * 8)];
#pragma unroll
        for (int sub = 0; sub < 2; sub++) {
          const s16x8 pf = *(const s16x8*)&Ps[w][(sub * 16 + l16) * 64 + (((4 * c + quad) ^ swz) * 8)];
          ol[sub] = __builtin_amdgcn_mfma_f32_16x16x32_bf16(pf, ones, ol[sub], 0, 0, 0);
#pragma unroll
          for (int j = 0; j < 4; j++)
            o[sub][j] = __builtin_amdgcn_mfma_f32_16x16x32_bf16(pf, vf[j], o[sub][j], 0, 0, 0);
        }
      }
      __builtin_amdgcn_s_setprio(0);
    }

    cur = (cur == 2) ? 0 : cur + 1;
    nx2 = (nx2 == 2) ? 0 : nx2 + 1;
  }

  // epilogue: normalize by ol[sub][r] (row sum, all lanes of the row identical)
#pragma unroll
  for (int sub = 0; sub < 2; sub++)
#pragma unroll
    for (int r = 0; r < 4; r++) {
      const float inv = 1.0f / ol[sub][r];
      const int q = q0b + w * 32 + sub * 16 + quad * 4 + r;
      short* ob = attout + ((size_t)(b * T_ + q) * H_ + h) * 64 + l16;
      ob[0]  = f2bf(o[sub][0][r] * inv);
      ob[16] = f2bf(o[sub][1][r] * inv);
      ob[32] = f2bf(o[sub][2][r] * inv);
      ob[48] = f2bf(o[sub][3][r] * inv);
    }
}

// ---------------- launch -----------------------------------------------------
extern "C" void kernel_launch(void* const* d_in, const int* in_sizes, int n_in,
                              void* d_out, int out_size, void* d_ws, size_t ws_size,
                              hipStream_t stream) {
  const float* x     = (const float*)d_in[0];   // [4096, 1024] fp32
  const float* wqkv  = (const float*)d_in[1];   // [3072, 1024] fp32
  const float* wproj = (const float*)d_in[2];   // [1024, 1024] fp32

  if (ws_size < 58720256u) return;
  short* ws     = (short*)d_ws;
  short* xb     = ws;                    // 4096*1024
  short* wqkvb  = xb + 4194304;          // 3072*1024
  short* wprojb = wqkvb + 3145728;       // 1024*1024
  short* qkv    = wprojb + 1048576;      // 4096*3072 (V third unused)
  short* vt     = qkv + 12582912;        // 2*16*64*2048
  short* attb   = vt + 4194304;          // 4096*1024

  castk_all<<<8192, 256, 0, stream>>>(x, wqkv, wproj, xb, wqkvb, wprojb);
  gemm_nt_128<2><<<dim3(24, 32), 256, 0, stream>>>(xb, wqkvb, qkv, vt, 4096, 3072, 1024);
  attn_kernel<<<dim3(32, 16), 256, 0, stream>>>(qkv, vt, attb);
  gemm_nt_128<0><<<dim3(8, 32), 256, 0, stream>>>(attb, wprojb, d_out, nullptr, 4096, 1024, 1024);
}

// Round 4
// 167.725 us; speedup vs baseline: 1.1170x; 1.1170x over previous
//
#include <hip/hip_runtime.h>
#include <stdint.h>
#include <stddef.h>

typedef __attribute__((ext_vector_type(8))) short s16x8;
typedef __attribute__((ext_vector_type(4))) short s16x4;
typedef __attribute__((ext_vector_type(4))) float f32x4;

#define B_  2
#define T_  2048
#define E_  1024
#define H_  16
#define E3_ 3072

// fp32 -> bf16, round-to-nearest-even
__device__ __forceinline__ short f2bf(float f) {
  union { float f; uint32_t u; } v; v.f = f;
  uint32_t u = v.u;
  return (short)((u + 0x7FFFu + ((u >> 16) & 1u)) >> 16);
}

__device__ __forceinline__ uint32_t fbits(float f) {
  union { float f; uint32_t u; } v; v.f = f; return v.u;
}

// async global->LDS, 16B per lane; lds dest = wave-uniform base + lane*16
__device__ __forceinline__ void gload_lds16(const short* g, short* l) {
  __builtin_amdgcn_global_load_lds(
      (__attribute__((address_space(1))) void*)(const_cast<short*>(g)),
      (__attribute__((address_space(3))) void*)(l), 16, 0, 0);
}

// ---------------- merged cast kernel (x, w_qkv, w_proj in one launch) -------
// Q-rows of w_qkv (first E rows) pre-scaled by log2(e)/8 so attention can
// call exp2f directly on MFMA output.
__global__ void castk_all(const float* __restrict__ x, const float* __restrict__ wqkv,
                          const float* __restrict__ wproj, short* __restrict__ xb,
                          short* __restrict__ wqkvb, short* __restrict__ wprojb) {
  const int bid = blockIdx.x;
  const float* in; short* out; int i; float sc = 1.0f;
  if (bid < 4096)      { in = x;     out = xb;     i = bid * 256 + threadIdx.x; }
  else if (bid < 7168) { in = wqkv;  out = wqkvb;  i = (bid - 4096) * 256 + threadIdx.x;
                         if (i < 262144) sc = 0.18033688011112042f; }
  else                 { in = wproj; out = wprojb; i = (bid - 7168) * 256 + threadIdx.x; }
  const float4 v = ((const float4*)in)[i];
  s16x4 o;
  o[0] = f2bf(v.x * sc); o[1] = f2bf(v.y * sc);
  o[2] = f2bf(v.z * sc); o[3] = f2bf(v.w * sc);
  ((s16x4*)out)[i] = o;
}

// ---------------- NT GEMM: C[M,N] = A[M,K] * B[N,K]^T (bf16 in, fp32 acc) ---
// MODE 0: fp32 output, plain. MODE 2: qkv mode — bf16 output; V columns
// (col >= 2E) are written TRANSPOSED into vt[b,h,d,t] (packed s16x4 over 4
// consecutive t), Q/K columns go to the qkv buffer. Fuses the old vtrans.
template <int MODE>
__global__ void gemm_nt_128(const short* __restrict__ A, const short* __restrict__ B,
                            void* __restrict__ Cv, short* __restrict__ vt,
                            int M, int N, int K) {
  __shared__ short As[128 * 32];
  __shared__ short Bs[128 * 32];
  const int tid  = threadIdx.x;
  const int lane = tid & 63;
  const int w    = tid >> 6;
  const int quad = lane >> 4;
  const int l16  = lane & 15;
  const int wm   = (w >> 1) * 64;
  const int wn   = (w & 1) * 64;
  const int bm   = blockIdx.y * 128;
  const int bn   = blockIdx.x * 128;

  f32x4 acc[4][4];
#pragma unroll
  for (int i = 0; i < 4; i++)
#pragma unroll
    for (int j = 0; j < 4; j++) acc[i][j] = (f32x4){0.f, 0.f, 0.f, 0.f};

  const int srow = w * 32 + (lane >> 2);
  const int scol = (lane & 3) * 8;
  const short* gA = A + (size_t)(bm + srow) * K + scol;
  const short* gB = B + (size_t)(bn + srow) * K + scol;
  short* lA = As + (w * 32) * 32;
  short* lB = Bs + (w * 32) * 32;

  for (int k0 = 0; k0 < K; k0 += 32) {
    __syncthreads();
    gload_lds16(gA + k0,          lA);
    gload_lds16(gA + 16 * K + k0, lA + 16 * 32);
    gload_lds16(gB + k0,          lB);
    gload_lds16(gB + 16 * K + k0, lB + 16 * 32);
    __syncthreads();

    s16x8 a[4], b[4];
#pragma unroll
    for (int i = 0; i < 4; i++)
      a[i] = *(const s16x8*)&As[(wm + i * 16 + l16) * 32 + quad * 8];
#pragma unroll
    for (int j = 0; j < 4; j++)
      b[j] = *(const s16x8*)&Bs[(wn + j * 16 + l16) * 32 + quad * 8];
#pragma unroll
    for (int i = 0; i < 4; i++)
#pragma unroll
      for (int j = 0; j < 4; j++)
        acc[i][j] = __builtin_amdgcn_mfma_f32_16x16x32_bf16(a[i], b[j], acc[i][j], 0, 0, 0);
  }

  if (MODE == 2 && bn >= 2 * E_) {
    // V block: write transposed to vt[b,h,d,t], 4 consecutive t per store
#pragma unroll
    for (int i = 0; i < 4; i++) {
      const int token = bm + wm + i * 16 + quad * 4;
      const int bb = token >> 11, t = token & (T_ - 1);
#pragma unroll
      for (int j = 0; j < 4; j++) {
        const int col = bn + wn + j * 16 + l16 - 2 * E_;  // h*64 + d
        s16x4 pk;
#pragma unroll
        for (int r = 0; r < 4; r++) pk[r] = f2bf(acc[i][j][r]);
        *(s16x4*)&vt[((size_t)(bb * H_ + (col >> 6)) * 64 + (col & 63)) * T_ + t] = pk;
      }
    }
  } else {
#pragma unroll
    for (int i = 0; i < 4; i++) {
      const int row0 = bm + wm + i * 16 + quad * 4;
#pragma unroll
      for (int j = 0; j < 4; j++) {
        const int col = bn + wn + j * 16 + l16;
#pragma unroll
        for (int r = 0; r < 4; r++) {
          const size_t idx = (size_t)(row0 + r) * N + col;
          if (MODE == 2) ((short*)Cv)[idx] = f2bf(acc[i][j][r]);
          else           ((float*)Cv)[idx] = acc[i][j][r];
        }
      }
    }
  }
}

// ---------------- flash attention -------------------------------------------
// R4 = R2's proven geometry/scheduling (4-wave 64-q blocks, 1024 triangular
// blocks, LPT snake, 4 blocks/CU, double-buffered K/V, __syncthreads) with the
// P LDS round-trip (write P -> lgkmcnt(0) -> read back) replaced by an
// in-register transpose (T12 adapted):
//  * QK^T output s[j][r] is S^T: per lane q = l16 (col), kv rows. Pack row
//    pairs with v_cvt_pk_bf16_f32 (8 ops), then 4x v_permlane32_swap_b32
//    produce PV B-operand fragments F[c] (lane l16 = q-row, quad = kv chunk).
//  * The residual lane+-16 permutation is absorbed into a K-row STORE
//    permutation sigma = swap bits 2&3 of row idx, applied for free via the
//    per-lane global source address of global_load_lds (LDS stays linear).
//    Scores then sit at position rows; the swap network emits F in ACTUAL kv
//    order, so V stays linear. Diag mask uses tau(quad) = swap(1<->2).
//  * PV: o[j] = mfma(vf, F) (V is A, P is B) -> O^T: per lane q = l16,
//    d = 16j+4quad+r. Row sums: ol = mfma(ones, F) -> every reg = sum[q=l16].
//    Epilogue: 4x packed s16x4 stores per lane (one q row, 4-contig d).
// Removes per wave-step: 4 b64 P-writes + 2 b128 P-reads + the mid-step
// lgkmcnt(0) hard sync; Ps buffer gone -> LDS 40->32KB.
__global__ void __launch_bounds__(256, 4)
attn_kernel(const short* __restrict__ qkv, const short* __restrict__ vt,
            short* __restrict__ attout) {
  __shared__ short Ks[2][64 * 64];  // [kv_pos][d], 16B-chunk swizzled, sigma row order
  __shared__ short Vs[2][64 * 64];  // [d][kv], 16B-chunk swizzled, linear kv
  const int tid  = threadIdx.x;
  const int lane = tid & 63;
  const int w    = tid >> 6;
  const int quad = lane >> 4;
  const int l16  = lane & 15;
  const int bh = blockIdx.x;
  const int b = bh >> 4, h = bh & 15;
  // LPT snake mapping: longest q-tiles dispatched first, per-CU sum uniform
  const int ya = blockIdx.y & 7, yb = blockIdx.y >> 3;
  const int qt = (3 - yb) * 8 + ((yb & 1) ? ya : (7 - ya));
  const int q0b = qt * 64;
  const int q0w = q0b + w * 16;
  const float NEG_INF = -__builtin_inff();

  const int srl = lane >> 3;
  const int sgc = ((lane & 7) ^ srl) * 8;
  const short* gK = qkv + (size_t)(b * T_) * E3_ + E_ + h * 64 + sgc;
  const short* gV = vt + (size_t)(bh * 64) * T_ + sgc;
  const int swz = (l16 & 7);

  s16x8 ones;
#pragma unroll
  for (int i = 0; i < 8; i++) ones[i] = (short)0x3F80;  // bf16 1.0

  auto stage = [&](int kv0s, int bf) {
#pragma unroll
    for (int i = 0; i < 2; i++) {
      const int r8 = w * 16 + i * 8;          // LDS row-chunk base
      const int rowp = r8 + srl;              // LDS row position
      // sigma: swap bits 2,3 of row index (K source only; V stays linear)
      const int rowk = (rowp & ~12) | ((rowp & 4) << 1) | ((rowp & 8) >> 1);
      gload_lds16(gK + (size_t)(kv0s + rowk) * E3_, &Ks[bf][r8 * 64]);
      gload_lds16(gV + (size_t)rowp * T_ + kv0s,    &Vs[bf][r8 * 64]);
    }
  };

  // Q B-fragments (pre-scaled): B[n=l16][k=quad*8+j], two k-chunks
  const short* qbase = qkv + (size_t)(b * T_ + q0w + l16) * E3_ + h * 64 + quad * 8;
  const s16x8 qf0 = *(const s16x8*)(qbase);
  const s16x8 qf1 = *(const s16x8*)(qbase + 32);

  f32x4 o[4]; f32x4 ol = (f32x4){0.f, 0.f, 0.f, 0.f};
#pragma unroll
  for (int j = 0; j < 4; j++) o[j] = (f32x4){0.f, 0.f, 0.f, 0.f};

  // prologue: stage kv tile 0 into buffer 0
  stage(0, 0);
  __syncthreads();

  for (int kv0 = 0, g = 0; kv0 <= q0b; kv0 += 64, g++) {
    const int cur = g & 1;

    // K A-fragments for this step
    s16x8 kf[2][4];
#pragma unroll
    for (int c = 0; c < 2; c++)
#pragma unroll
      for (int j = 0; j < 4; j++)
        kf[c][j] = *(const s16x8*)&Ks[cur][(j * 16 + l16) * 64 + (((c * 4 + quad) ^ swz) * 8)];

    // prefetch next tile's DMA (hidden under this step's compute)
    if (kv0 + 64 <= q0b) stage(kv0 + 64, cur ^ 1);

    // S^T tile: s[j][r] = score[kv_pos = 16j+4quad+r][q = q0w+l16]
    f32x4 s[4];
#pragma unroll
    for (int j = 0; j < 4; j++) s[j] = (f32x4){0.f, 0.f, 0.f, 0.f};
    __builtin_amdgcn_s_setprio(1);
#pragma unroll
    for (int c = 0; c < 2; c++)
#pragma unroll
      for (int j = 0; j < 4; j++)
        s[j] = __builtin_amdgcn_mfma_f32_16x16x32_bf16(kf[c][j], c == 0 ? qf0 : qf1, s[j], 0, 0, 0);
    __builtin_amdgcn_s_setprio(0);

    // mask only on the diagonal step; actual kv = 16j + 4*tau(quad) + r
    if (kv0 == q0b) {
      const int tq4 = ((quad & 1) << 3) | ((quad >> 1) << 2);
#pragma unroll
      for (int j = 0; j < 4; j++)
#pragma unroll
        for (int r = 0; r < 4; r++)
          if (j * 16 + tq4 + r > w * 16 + l16) s[j][r] = NEG_INF;
    }

    // exp2 in place
#pragma unroll
    for (int j = 0; j < 4; j++) {
      s[j][0] = exp2f(s[j][0]); s[j][1] = exp2f(s[j][1]);
      s[j][2] = exp2f(s[j][2]); s[j][3] = exp2f(s[j][3]);
    }

    // pack row pairs -> bf16 dwords (dst.lo = src0)
    int dj[4][2];
#pragma unroll
    for (int j = 0; j < 4; j++) {
      asm("v_cvt_pk_bf16_f32 %0, %1, %2" : "=v"(dj[j][0]) : "v"(s[j][0]), "v"(s[j][1]));
      asm("v_cvt_pk_bf16_f32 %0, %1, %2" : "=v"(dj[j][1]) : "v"(s[j][2]), "v"(s[j][3]));
    }

    // 2x permlane32_swap per kv32 chunk -> B-operand fragments in actual-kv order
    s16x8 F[2];
#pragma unroll
    for (int c = 0; c < 2; c++) {
      int x0 = dj[2 * c][0], y0 = dj[2 * c + 1][0];
      int x1 = dj[2 * c][1], y1 = dj[2 * c + 1][1];
      asm("v_permlane32_swap_b32 %0, %1" : "+v"(x0), "+v"(y0));
      asm("v_permlane32_swap_b32 %0, %1" : "+v"(x1), "+v"(y1));
      union { int i4[4]; s16x8 v; } u;
      u.i4[0] = x0; u.i4[1] = x1; u.i4[2] = y0; u.i4[3] = y1;
      F[c] = u.v;
    }

    // O^T += V^T P^T ; row sums via ones-MFMA (every reg = sum of lane's q)
    __builtin_amdgcn_s_setprio(1);
#pragma unroll
    for (int c = 0; c < 2; c++) {
      ol = __builtin_amdgcn_mfma_f32_16x16x32_bf16(ones, F[c], ol, 0, 0, 0);
#pragma unroll
      for (int j = 0; j < 4; j++) {
        const s16x8 vf = *(const s16x8*)&Vs[cur][(j * 16 + l16) * 64 + (((c * 4 + quad) ^ swz) * 8)];
        o[j] = __builtin_amdgcn_mfma_f32_16x16x32_bf16(vf, F[c], o[j], 0, 0, 0);
      }
    }
    __builtin_amdgcn_s_setprio(0);

    __syncthreads();  // drains prefetch (covered by compute) + WAR fence
  }

  // epilogue: lane owns q = q0w + l16; o[j][r] = O[q][d = 16j+4quad+r]
  const float inv = 1.0f / ol[0];
  const int q = q0w + l16;
  short* ob = attout + ((size_t)(b * T_ + q) * H_ + h) * 64 + quad * 4;
#pragma unroll
  for (int j = 0; j < 4; j++) {
    s16x4 pk;
#pragma unroll
    for (int r = 0; r < 4; r++) pk[r] = f2bf(o[j][r] * inv);
    *(s16x4*)&ob[16 * j] = pk;
  }
}

// ---------------- launch -----------------------------------------------------
extern "C" void kernel_launch(void* const* d_in, const int* in_sizes, int n_in,
                              void* d_out, int out_size, void* d_ws, size_t ws_size,
                              hipStream_t stream) {
  const float* x     = (const float*)d_in[0];   // [4096, 1024] fp32
  const float* wqkv  = (const float*)d_in[1];   // [3072, 1024] fp32
  const float* wproj = (const float*)d_in[2];   // [1024, 1024] fp32

  if (ws_size < 58720256u) return;
  short* ws     = (short*)d_ws;
  short* xb     = ws;                    // 4096*1024
  short* wqkvb  = xb + 4194304;          // 3072*1024
  short* wprojb = wqkvb + 3145728;       // 1024*1024
  short* qkv    = wprojb + 1048576;      // 4096*3072 (V third unused)
  short* vt     = qkv + 12582912;        // 2*16*64*2048
  short* attb   = vt + 4194304;          // 4096*1024

  castk_all<<<8192, 256, 0, stream>>>(x, wqkv, wproj, xb, wqkvb, wprojb);
  gemm_nt_128<2><<<dim3(24, 32), 256, 0, stream>>>(xb, wqkvb, qkv, vt, 4096, 3072, 1024);
  attn_kernel<<<dim3(32, 32), 256, 0, stream>>>(qkv, vt, attb);
  gemm_nt_128<0><<<dim3(8, 32), 256, 0, stream>>>(attb, wprojb, d_out, nullptr, 4096, 1024, 1024);
}